// Round 10
// baseline (1066.557 us; speedup 1.0000x reference)
//
#include <hip/hip_runtime.h>
#include <hip/hip_bf16.h>
#include <math.h>

// Dims: E=512 M=1024 T=1024 H=512 V=10000 ; B=16 S=80 L=200 ; K=10

typedef __bf16 bf16x8 __attribute__((ext_vector_type(8)));
typedef float f32x4 __attribute__((ext_vector_type(4)));
typedef unsigned short u16x8 __attribute__((ext_vector_type(8)));

__device__ inline unsigned short f2b(float f){
  union { float f; unsigned u; } v; v.f = f;
  unsigned u = v.u;
  u += 0x7fff + ((u >> 16) & 1);       // round-to-nearest-even
  return (unsigned short)(u >> 16);
}
__device__ inline float b2f(unsigned short u){
  union { unsigned u; float f; } v; v.u = (unsigned)u << 16; return v.f;
}
__device__ inline float sigm(float x){ return 1.f/(1.f + __expf(-x)); }
__device__ inline float tanh_fast(float x){
  float e = __expf(2.f*x);
  return 1.f - 2.f/(e + 1.f);
}
__device__ inline float wred_max(float v){ for (int o=32;o;o>>=1) v = fmaxf(v, __shfl_xor(v,o)); return v; }
__device__ inline float wred_sum(float v){ for (int o=32;o;o>>=1) v += __shfl_xor(v,o); return v; }

__device__ inline float bred_max(float v, float* sm){
  v = wred_max(v);
  int w = threadIdx.x >> 6;
  if ((threadIdx.x & 63) == 0) sm[w] = v;
  __syncthreads();
  v = fmaxf(fmaxf(sm[0], sm[1]), fmaxf(sm[2], sm[3]));
  __syncthreads();
  return v;
}
__device__ inline float bred_sum(float v, float* sm){
  v = wred_sum(v);
  int w = threadIdx.x >> 6;
  if ((threadIdx.x & 63) == 0) sm[w] = v;
  __syncthreads();
  v = sm[0] + sm[1] + sm[2] + sm[3];
  __syncthreads();
  return v;
}

#define GLOAD_LDS16(g, l) __builtin_amdgcn_global_load_lds( \
    (const __attribute__((address_space(1))) void*)(g), \
    (__attribute__((address_space(3))) void*)(l), 16, 0, 0)

// ---------------------------------------------------------------------------
// Fused f32->bf16 conversion pass (7 tensors) + bar zero + m0fused tail.
// Blocks [0,3776): conversion chunks; blocks [3776,3904): avgpool+m0 GEMV.
// (m0 depends only on raw attt/attm; merged here to save a ~10us launch.)
// ---------------------------------------------------------------------------
__global__ void cvt7m_kernel(
    const float* __restrict__ attm, const float* __restrict__ attt,
    const float* __restrict__ Wm,   const float* __restrict__ Wt,
    const float* __restrict__ Wmm,  const float* __restrict__ Wih,
    const float* __restrict__ emb,
    unsigned short* __restrict__ attm_bf, unsigned short* __restrict__ attt_bf,
    unsigned short* __restrict__ Wm_bf,   unsigned short* __restrict__ Wt_bf,
    unsigned short* __restrict__ Wmm_bf,  unsigned short* __restrict__ Wih_bf,
    unsigned short* __restrict__ mm_inp_bf,
    const float* __restrict__ Wli, const float* __restrict__ bli,
    unsigned short* __restrict__ m0_bf, int* __restrict__ bar)
{
  if (blockIdx.x >= 3776){
    // ---- m0fused path: avgpool row (204) into LDS + 512-col GEMV ----
    __shared__ float rowv[204];
    int bx = blockIdx.x - 3776, tid = threadIdx.x;
    int b = bx >> 3, s = bx & 7;
    if (tid < 204){
      int c = tid;
      const float* src = (c < 102) ? (attt + ((size_t)(b*80 + s*10))*1024 + c*10)
                                   : (attm + ((size_t)(b*80 + s*10))*1024 + (c-102)*10);
      float acc = 0.f;
      for (int r=0;r<10;r++){
        const float* p = src + (size_t)r*1024;
#pragma unroll
        for (int cc=0;cc<10;cc++) acc += p[cc];
      }
      rowv[c] = acc * 0.01f;
    }
    __syncthreads();
    for (int c = tid; c < 512; c += 256){
      const float* w = Wli + (size_t)c*204;
      float acc = bli[c];
      for (int k=0;k<204;k++) acc += rowv[k]*w[k];
      m0_bf[(size_t)bx*512 + c] = f2b(acc);
    }
    return;
  }
  int i = blockIdx.x*256 + threadIdx.x;
  if (blockIdx.x == 0 && threadIdx.x < 128) bar[threadIdx.x] = 0;
  const float* s; unsigned short* d; int o;
  if (i < 458752){
    if (i < 163840){ s = attm; d = attm_bf; o = i; }
    else if (i < 327680){ s = attt; d = attt_bf; o = i - 163840; }
    else { s = Wm; d = Wm_bf; o = i - 327680; }
  } else if (i < 753664){
    if (i < 589824){ s = Wt; d = Wt_bf; o = i - 458752; }
    else { s = Wmm; d = Wmm_bf; o = i - 589824; }
  } else {
    if (i < 884736){ s = Wih; d = Wih_bf; o = i - 753664; }
    else { s = emb; d = mm_inp_bf; o = i - 884736; }
  }
  f32x4 a = ((const f32x4*)s)[(size_t)o*2];
  f32x4 b = ((const f32x4*)s)[(size_t)o*2+1];
  u16x8 v;
  v[0]=f2b(a[0]); v[1]=f2b(a[1]); v[2]=f2b(a[2]); v[3]=f2b(a[3]);
  v[4]=f2b(b[0]); v[5]=f2b(b[1]); v[6]=f2b(b[2]); v[7]=f2b(b[3]);
  if (i >= 884736){
    int row = o >> 6, c8 = (o & 63) << 3;
    *(u16x8*)&d[(size_t)row*2560 + c8] = v;
  } else {
    ((u16x8*)d)[o] = v;
  }
}

// ---------------------------------------------------------------------------
// Shared GEMM body: C = A @ B^T + b1 + b2.  A:(R,K) bf16, B:(N,K) bf16.
// Output: f32 to C, or bf16 to Cbf if Cbf != nullptr.
// 128x128 tile, BK=32, 256 thr. global_load_lds staging.
// ---------------------------------------------------------------------------
__device__ __forceinline__ void gemm_body(
    const unsigned short* __restrict__ A, const unsigned short* __restrict__ B,
    const float* __restrict__ bias1, const float* __restrict__ bias2,
    float* __restrict__ C, unsigned short* __restrict__ Cbf, int N, int K,
    unsigned short* lA, unsigned short* lB, int r0, int n0)
{
  int tid = threadIdx.x;
  int w = tid >> 6, lane = tid & 63;
  int wr = (w >> 1) << 6, wc = (w & 1) << 6;
  int lm = lane & 15, lq = lane >> 4;
  f32x4 acc[4][4] = {};

  int row0 = tid >> 2, row1 = (tid + 256) >> 2, cc = (tid & 3) << 3;
  const unsigned short* Ag0 = A + (size_t)(r0 + row0)*K + cc;
  const unsigned short* Ag1 = A + (size_t)(r0 + row1)*K + cc;
  int br0 = n0 + row0; if (br0 >= N) br0 = N - 1;
  int br1 = n0 + row1; if (br1 >= N) br1 = N - 1;
  const unsigned short* Bg0 = B + (size_t)br0*K + cc;
  const unsigned short* Bg1 = B + (size_t)br1*K + cc;
  unsigned lb0 = (unsigned)(tid & ~63) * 8;   // u16 index, wave-uniform
  unsigned lb1 = 2048 + lb0;

  for (int k0 = 0; k0 < K; k0 += 32){
    GLOAD_LDS16(Ag0 + k0, &lA[lb0]);
    GLOAD_LDS16(Ag1 + k0, &lA[lb1]);
    GLOAD_LDS16(Bg0 + k0, &lB[lb0]);
    GLOAD_LDS16(Bg1 + k0, &lB[lb1]);
    __syncthreads();
    bf16x8 af[4], bfr[4];
#pragma unroll
    for (int i=0;i<4;i++){
      af[i]  = *(const bf16x8*)&lA[(wr + i*16 + lm)*32 + lq*8];
      bfr[i] = *(const bf16x8*)&lB[(wc + i*16 + lm)*32 + lq*8];
    }
#pragma unroll
    for (int i=0;i<4;i++)
#pragma unroll
      for (int j=0;j<4;j++)
        acc[i][j] = __builtin_amdgcn_mfma_f32_16x16x32_bf16(af[i], bfr[j], acc[i][j], 0, 0, 0);
    __syncthreads();
  }
#pragma unroll
  for (int i=0;i<4;i++){
    int rbase = r0 + wr + i*16 + lq*4;
#pragma unroll
    for (int j=0;j<4;j++){
      int n = n0 + wc + j*16 + lm;
      if (n < N){
        float bv = (bias1 ? bias1[n] : 0.f) + (bias2 ? bias2[n] : 0.f);
        if (Cbf){
#pragma unroll
          for (int rr=0;rr<4;rr++)
            Cbf[(size_t)(rbase + rr)*N + n] = f2b(acc[i][j][rr] + bv);
        } else {
#pragma unroll
          for (int rr=0;rr<4;rr++)
            C[(size_t)(rbase + rr)*N + n] = acc[i][j][rr] + bv;
        }
      }
    }
  }
}

__global__ __launch_bounds__(256) void gemm_bb_kernel(
    const unsigned short* __restrict__ A, const unsigned short* __restrict__ B,
    const float* __restrict__ bias1, const float* __restrict__ bias2,
    float* __restrict__ C, unsigned short* __restrict__ Cbf, int N, int K)
{
  __shared__ unsigned short lA[128*32];
  __shared__ unsigned short lB[128*32];
  gemm_body(A, B, bias1, bias2, C, Cbf, N, K, lA, lB, blockIdx.x << 7, blockIdx.y << 7);
}

// two same-shape GEMMs + f_m/f_t projection plane in one launch.
// grid (10,8,3): z=0 GEMM0, z=1 GEMM1, z=2 -> 80 blocks of f-projections
// (f only needs mfeat/tfeat/Ws*; co-runs with the GEMMs on idle CUs).
__global__ __launch_bounds__(256) void gemm_bb2f_kernel(
    const unsigned short* __restrict__ A0, const unsigned short* __restrict__ B0,
    const float* __restrict__ b0, float* __restrict__ C0,
    const unsigned short* __restrict__ A1, const unsigned short* __restrict__ B1,
    const float* __restrict__ b1, float* __restrict__ C1, int N, int K,
    const float* __restrict__ mfeat, const float* __restrict__ tfeat,
    const float* __restrict__ Wsm, const float* __restrict__ Wst,
    float* __restrict__ f_m, float* __restrict__ f_t)
{
  __shared__ unsigned short lA[128*32];
  __shared__ unsigned short lB[128*32];
  if (blockIdx.z == 0){ gemm_body(A0, B0, b0, nullptr, C0, nullptr, N, K, lA, lB, blockIdx.x << 7, blockIdx.y << 7); return; }
  if (blockIdx.z == 1){ gemm_body(A1, B1, b1, nullptr, C1, nullptr, N, K, lA, lB, blockIdx.x << 7, blockIdx.y << 7); return; }
  // z == 2: f_m[r] = dot(mfeat[r], Wsm[512:1536)); f_t likewise. 6400 wave-rows.
  int flat = blockIdx.x*8 + blockIdx.y;     // 0..79
  int lane = threadIdx.x & 63;
  int wv = flat*4 + (threadIdx.x >> 6);     // 0..319
  for (int r = wv; r < 6400; r += 320){
    const float* a = (r < 3200) ? (mfeat + (size_t)r*1024) : (tfeat + (size_t)(r-3200)*1024);
    const float* wvec = (r < 3200) ? (Wsm + 512) : (Wst + 512);
    float acc = 0.f;
    for (int c = lane; c < 1024; c += 64) acc += a[c]*wvec[c];
    acc = wred_sum(acc);
    if (lane == 0){ if (r < 3200) f_m[r] = acc; else f_t[r-3200] = acc; }
  }
}

// X1 (128x2048, A=m0_bf) and X2 (1280x2048, A=mm_out_bf) in one launch.
// grid (11,16): x==0 -> X1 tile; x in [1,10] -> X2 row-tile x-1.
__global__ __launch_bounds__(256) void gemm_x12_kernel(
    const unsigned short* __restrict__ m0_bf, const unsigned short* __restrict__ mmo_bf,
    const unsigned short* __restrict__ Wih_bf,
    const float* __restrict__ bih, const float* __restrict__ bhh,
    float* __restrict__ X1, float* __restrict__ X2)
{
  __shared__ unsigned short lA[128*32];
  __shared__ unsigned short lB[128*32];
  if (blockIdx.x == 0)
    gemm_body(m0_bf, Wih_bf, bih, bhh, X1, nullptr, 2048, 512, lA, lB, 0, blockIdx.y << 7);
  else
    gemm_body(mmo_bf, Wih_bf, bih, bhh, X2, nullptr, 2048, 512, lA, lB, (blockIdx.x - 1) << 7, blockIdx.y << 7);
}

// ---------------------------------------------------------------------------
// y = x * softmax(x) over rows of 1024; merged pair -> bf16 into mm_inp cols
// ---------------------------------------------------------------------------
__global__ __launch_bounds__(256) void rowsmx2_kernel(const float* __restrict__ X0,
    const float* __restrict__ X1, unsigned short* __restrict__ out)
{
  __shared__ float sm[4];
  int bx = blockIdx.x, tid = threadIdx.x;
  int row = (bx < 1280) ? bx : bx - 1280;
  const float* xr = ((bx < 1280) ? X0 : X1) + (size_t)row * 1024;
  int ooff = (bx < 1280) ? 1536 : 512;
  float x[4];
#pragma unroll
  for (int j=0;j<4;j++) x[j] = xr[j*256 + tid];
  float m = fmaxf(fmaxf(x[0],x[1]), fmaxf(x[2],x[3]));
  m = bred_max(m, sm);
  float s = 0.f;
#pragma unroll
  for (int j=0;j<4;j++) s += __expf(x[j]-m);
  s = bred_sum(s, sm);
  float inv = 1.f / s;
  unsigned short* o = out + (size_t)row*2560 + ooff;
#pragma unroll
  for (int j=0;j<4;j++) o[j*256 + tid] = f2b(x[j] * (__expf(x[j]-m) * inv));
}

// ---------------------------------------------------------------------------
// Persistent fused LSTM -- round-0 protocol, full-h exchange (b*128 stride).
// r5-r9 conclusion: correct-exchange floor is ~350-360us; r7's arrangement
// (Wo f32->bf16 as UNPACED nontemporal helper) was the measured optimum --
// interference ~6us << ~37us of doing the conversion serially. f_m/f_t
// moved to the bb2 launch (r9: they cost ~5us here). act stored bf16-only.
// ---------------------------------------------------------------------------
#define LSTM_NBLK 32
#define HP 520   // padded row stride (u16 elems)

__global__ __launch_bounds__(256) void lstm_fused_kernel(
    const float* __restrict__ X1, const float* __restrict__ X2,
    const float* __restrict__ Whh,
    unsigned long long* __restrict__ hb0, unsigned long long* __restrict__ hb1,
    unsigned short* __restrict__ finalA_bf,
    int* __restrict__ bar,
    const float* __restrict__ Wo, unsigned short* __restrict__ Wo_bf)
{
  __shared__ unsigned short w_lds[64*HP];   // 66560 B
  __shared__ unsigned short h_lds[16*HP];   // 16640 B
  __shared__ float gb[4][16][16];           // 4096 B
  __shared__ unsigned short hstage[16][16]; // 512 B [batch][unit]
  int tid = threadIdx.x, j = blockIdx.x;

  if (j >= LSTM_NBLK){
    // ---- helper blocks: Wo f32 -> bf16, nontemporal reads, unpaced (r7) ----
    int hb = j - LSTM_NBLK;                 // 0..223
    const f32x4* wp = (const f32x4*)Wo;
    for (int ch = hb*256 + tid; ch < 3200000; ch += 224*256){
      f32x4 a = __builtin_nontemporal_load(wp + (size_t)ch*2);
      f32x4 b = __builtin_nontemporal_load(wp + (size_t)ch*2 + 1);
      u16x8 o;
      o[0]=f2b(a[0]); o[1]=f2b(a[1]); o[2]=f2b(a[2]); o[3]=f2b(a[3]);
      o[4]=f2b(b[0]); o[5]=f2b(b[1]); o[6]=f2b(b[2]); o[7]=f2b(b[3]);
      ((u16x8*)Wo_bf)[ch] = o;              // cached: Wo GEMM re-reads from LLC
    }
    return;
  }

  // ---------------- recurrence blocks: round-0 protocol ----------------
  int j16 = j*16;
  int lane = tid & 63, w = tid >> 6;
  int lm = lane & 15, lq = lane >> 4;

  // ---- preload Whh slice (rows g*512 + j16 + u), f32 -> bf16, once ----
  for (int i = 0; i < 16; i++){
    int ch = tid + i*256;              // 4096 chunks of 8
    int r = ch >> 6, c8 = (ch & 63) << 3;
    int grow = (r >> 4)*512 + j16 + (r & 15);
    const float* s = Whh + (size_t)grow*512 + c8;
    f32x4 a = ((const f32x4*)s)[0], b = ((const f32x4*)s)[1];
    u16x8 o;
    o[0]=f2b(a[0]); o[1]=f2b(a[1]); o[2]=f2b(a[2]); o[3]=f2b(a[3]);
    o[4]=f2b(b[0]); o[5]=f2b(b[1]); o[6]=f2b(b[2]); o[7]=f2b(b[3]);
    *(u16x8*)&w_lds[r*HP + c8] = o;
  }

  float c_reg = 0.f;
  int ul = tid & 15, bb = tid >> 4;
  unsigned long long* hbufs[2] = { hb0, hb1 };
  const int wbase = ((w << 4) + lm)*HP;
  const int abase = lm*HP;
  const int koff = lq << 3;
  int sc = 0;

  for (int seg = 0; seg < 2; seg++){
    const float* Xp = seg ? X2 : X1;
    int Tst = seg ? 80 : 8;
    for (int t = 0; t < Tst; t++){
      // ---- wait for previous step's h to be at the LLC ----
      if (sc > 0){
        if (tid == 0){
          while (__hip_atomic_load(&bar[sc-1], __ATOMIC_RELAXED, __HIP_MEMORY_SCOPE_AGENT) < LSTM_NBLK)
            __builtin_amdgcn_s_sleep(1);
        }
        __syncthreads();
      }
      // ---- X gate biases for this step (independent of h; overlaps h load) ----
      size_t xrow = ((size_t)bb*Tst + t)*2048 + j16 + ul;
      float xi = Xp[xrow];
      float xf = Xp[xrow + 512];
      float xg = Xp[xrow + 1024];
      float xo = Xp[xrow + 1536];
      // ---- load h state into LDS (LLC-coherent atomic loads) ----
      if (sc == 0){
        u16x8 z = {0,0,0,0,0,0,0,0};
        for (int i = tid; i < 1024; i += 256){
          int b = i >> 6, c8 = (i & 63) << 3;
          *(u16x8*)&h_lds[b*HP + c8] = z;
        }
      } else {
        const unsigned long long* src = hbufs[sc & 1];
#pragma unroll
        for (int it = 0; it < 8; it++){
          int i = tid + it*256;               // u64 chunk: b = i>>7, c64 = i&127
          int b = i >> 7, c64 = i & 127;
          unsigned long long v = __hip_atomic_load(&src[i], __ATOMIC_RELAXED, __HIP_MEMORY_SCOPE_AGENT);
          *(unsigned long long*)&h_lds[b*HP + (c64 << 2)] = v;
        }
      }
      __syncthreads();
      // ---- gates: wave w computes gate w for 16 units x 16 batches ----
      f32x4 a0 = {0.f,0.f,0.f,0.f}, a1 = {0.f,0.f,0.f,0.f};
#pragma unroll
      for (int k0 = 0; k0 < 512; k0 += 64){
        bf16x8 ha = *(const bf16x8*)&h_lds[abase + k0 + koff];
        bf16x8 wa = *(const bf16x8*)&w_lds[wbase + k0 + koff];
        a0 = __builtin_amdgcn_mfma_f32_16x16x32_bf16(ha, wa, a0, 0, 0, 0);
        bf16x8 hbf = *(const bf16x8*)&h_lds[abase + k0 + 32 + koff];
        bf16x8 wbf = *(const bf16x8*)&w_lds[wbase + k0 + 32 + koff];
        a1 = __builtin_amdgcn_mfma_f32_16x16x32_bf16(hbf, wbf, a1, 0, 0, 0);
      }
      f32x4 acc = a0 + a1;
      *(f32x4*)&gb[w][lm][lq << 2] = acc;   // gb[gate][unit][batch]
      __syncthreads();
      // ---- cell update: thread = (batch bb, unit ul) ----
      float iv = gb[0][ul][bb] + xi;
      float fv = gb[1][ul][bb] + xf;
      float gv = gb[2][ul][bb] + xg;
      float ov = gb[3][ul][bb] + xo;
      c_reg = sigm(fv)*c_reg + sigm(iv)*tanh_fast(gv);
      float hn = sigm(ov)*tanh_fast(c_reg);
      hstage[bb][ul] = f2b(hn);
      __syncthreads();
      // ---- publish h slice to LLC (wave 0: 64 x 8B coherent stores) ----
      if (tid < 64){
        int b = tid >> 2, ch = tid & 3;
        unsigned long long v = *(const unsigned long long*)&hstage[b][ch << 2];
        unsigned long long* dst = hbufs[(sc + 1) & 1] + (size_t)b*128 + (j << 2) + ch;
        __hip_atomic_store(dst, v, __ATOMIC_RELAXED, __HIP_MEMORY_SCOPE_AGENT);
      }
      sc++;
      __syncthreads();   // vmcnt(0) drain: h publish ack'd at LLC
      if (tid == 0)
        __hip_atomic_fetch_add(&bar[sc-1], 1, __ATOMIC_RELAXED, __HIP_MEMORY_SCOPE_AGENT);
      // act store AFTER the flag: off the cross-block critical path
      if (seg)
        finalA_bf[(size_t)(bb*80 + t)*2560 + j16 + ul] = f2b(tanh_fast(hn));
    }
  }
}

// ---------------------------------------------------------------------------
// fused attention scores: e = act[:, :512] @ we + b (bf16 act), then masked
// softmax over (e + f).  2560 blocks: [0,1280) tempo, [1280,2560) motion.
// ---------------------------------------------------------------------------
__global__ __launch_bounds__(256) void attscore_kernel(
    const unsigned short* __restrict__ finalA_bf,
    const float* __restrict__ Wsm, const float* __restrict__ bsm,
    const float* __restrict__ Wst, const float* __restrict__ bst,
    const float* __restrict__ f_m, const float* __restrict__ f_t,
    const int* __restrict__ lens_m, const int* __restrict__ lens_t,
    float* __restrict__ w_m, float* __restrict__ w_t)
{
  __shared__ float sm[4];
  int bx = blockIdx.x, tid = threadIdx.x;
  bool mside = bx >= 1280;
  int row = mside ? bx - 1280 : bx;
  const float* wv = mside ? Wsm : Wst;
  float bias = (mside ? bsm : bst)[0];
  const float* f = mside ? f_m : f_t;
  const int* lens = mside ? lens_m : lens_t;
  float* w = mside ? w_m : w_t;
  const unsigned short* a = finalA_bf + (size_t)row*2560;
  float d = b2f(a[tid])*wv[tid] + b2f(a[256+tid])*wv[256+tid];
  float e = bred_sum(d, sm) + bias;
  int b = row/80;
  int len = lens[b];
  bool ok = (tid < 200) && (tid < len);
  float val = ok ? (e + f[b*200 + tid]) : -1e30f;
  float m = bred_max(val, sm);
  float ex = ok ? __expf(val - m) : 0.f;
  float s = bred_sum(ex, sm);
  if (tid < 200) w[(size_t)row*200 + tid] = ex / s;
}

// out[b, s, :] = sum_l w[b,s,l] * feats[b,l,:] -> bf16 into finalA_bf.
// grid (16,10,2): z=0 tempo->cols[512,1536), z=1 motion->cols[1536,2560)
__global__ __launch_bounds__(256) void attapply_kernel(
    const float* __restrict__ w_t, const float* __restrict__ w_m,
    const float* __restrict__ tfeat, const float* __restrict__ mfeat,
    unsigned short* __restrict__ finalA_bf)
{
  __shared__ float lw[8][200];
  int b = blockIdx.x, sg = blockIdx.y, z = blockIdx.z;
  const float* w = z ? w_m : w_t;
  const float* feats = z ? mfeat : tfeat;
  int coloff = z ? 1536 : 512;
  int tid = threadIdx.x;
  for (int i = tid; i < 1600; i += 256){
    int ss = i / 200, l = i - ss*200;
    lw[ss][l] = w[(size_t)(b*80 + sg*8 + ss)*200 + l];
  }
  __syncthreads();
  float4 acc[8];
#pragma unroll
  for (int s=0;s<8;s++) acc[s] = make_float4(0,0,0,0);
  const float* fb = feats + (size_t)b*200*1024 + tid*4;
  for (int l=0;l<200;l++){
    float4 v = *(const float4*)(fb + (size_t)l*1024);
#pragma unroll
    for (int s=0;s<8;s++){
      float wv = lw[s][l];
      acc[s].x += wv*v.x; acc[s].y += wv*v.y; acc[s].z += wv*v.z; acc[s].w += wv*v.w;
    }
  }
#pragma unroll
  for (int s=0;s<8;s++){
    ushort4 o;
    o.x = f2b(acc[s].x); o.y = f2b(acc[s].y); o.z = f2b(acc[s].z); o.w = f2b(acc[s].w);
    *(ushort4*)&finalA_bf[(size_t)(b*80 + sg*8 + s)*2560 + coloff + tid*4] = o;
  }
}

// in-place log_softmax over rows of 10000 -- no row buffer (row stays L2-hot;
// LDS-free -> occupancy not LDS-bound on a 1280-block launch)
__global__ __launch_bounds__(256) void logsmax_kernel(float* __restrict__ out)
{
  __shared__ float sm[4];
  int row = blockIdx.x, tid = threadIdx.x;
  float* o = out + (size_t)row * 10000;
  float m = -1e30f;
  for (int i = tid; i < 10000; i += 256) m = fmaxf(m, o[i]);
  m = bred_max(m, sm);
  float s = 0.f;
  for (int i = tid; i < 10000; i += 256) s += __expf(o[i] - m);
  s = bred_sum(s, sm);
  float lse = m + __logf(s);
  for (int i = tid; i < 10000; i += 256) o[i] = o[i] - lse;
}

// ---------------------------------------------------------------------------
extern "C" void kernel_launch(void* const* d_in, const int* in_sizes, int n_in,
                              void* d_out, int out_size, void* d_ws, size_t ws_size,
                              hipStream_t stream)
{
  const float* mfeat = (const float*)d_in[0];
  const float* tfeat = (const float*)d_in[1];
  const float* attm  = (const float*)d_in[2];
  const float* attt  = (const float*)d_in[3];
  const float* emb   = (const float*)d_in[4];
  const int* lens_m  = (const int*)d_in[5];
  const int* lens_t  = (const int*)d_in[6];
  const float* Wm  = (const float*)d_in[8];
  const float* bm  = (const float*)d_in[9];
  const float* Wt  = (const float*)d_in[10];
  const float* bt  = (const float*)d_in[11];
  const float* Wmm = (const float*)d_in[12];
  const float* bmm = (const float*)d_in[13];
  const float* Wli = (const float*)d_in[14];
  const float* bli = (const float*)d_in[15];
  const float* Wih = (const float*)d_in[16];
  const float* Whh = (const float*)d_in[17];
  const float* bih = (const float*)d_in[18];
  const float* bhh = (const float*)d_in[19];
  const float* Wsm = (const float*)d_in[20];
  const float* bsm = (const float*)d_in[21];
  const float* Wst = (const float*)d_in[22];
  const float* bst = (const float*)d_in[23];
  const float* Wo  = (const float*)d_in[24];
  const float* bo  = (const float*)d_in[25];
  float* out = (float*)d_out;

  char* ws = (char*)d_ws;
  size_t off = 0;
  auto alloc = [&](size_t bytes)->void* {
    void* p = (void*)(ws + off);
    off += (bytes + 255) & ~(size_t)255;
    return p;
  };
  // f32 scratch
  float* moutp  = (float*)alloc(1280UL*1024*4);
  float* toutp  = (float*)alloc(1280UL*1024*4);
  float* X1     = (float*)alloc(128UL*2048*4);
  float* X2     = (float*)alloc(1280UL*2048*4);
  float* f_m = (float*)alloc(3200UL*4); float* f_t = (float*)alloc(3200UL*4);
  float* w_m = (float*)alloc(1280UL*200*4); float* w_t = (float*)alloc(1280UL*200*4);
  int* bar = (int*)alloc(128*4);
  // bf16 / u64 scratch
  unsigned long long* hbuf0 = (unsigned long long*)alloc(16UL*128*8);
  unsigned long long* hbuf1 = (unsigned long long*)alloc(16UL*128*8);
  unsigned short* attm_bf   = (unsigned short*)alloc(1280UL*1024*2);
  unsigned short* attt_bf   = (unsigned short*)alloc(1280UL*1024*2);
  unsigned short* Wm_bf     = (unsigned short*)alloc(1024UL*1024*2);
  unsigned short* Wt_bf     = (unsigned short*)alloc(1024UL*1024*2);
  unsigned short* Wmm_bf    = (unsigned short*)alloc(512UL*2560*2);
  unsigned short* Wih_bf    = (unsigned short*)alloc(2048UL*512*2);
  unsigned short* Wo_bf     = (unsigned short*)alloc(10000UL*2560*2);
  unsigned short* mm_inp_bf = (unsigned short*)alloc(1280UL*2560*2);
  unsigned short* mm_out_bf = (unsigned short*)alloc(1280UL*512*2);
  unsigned short* m0_bf     = (unsigned short*)alloc(128UL*512*2);
  unsigned short* finalA_bf = (unsigned short*)alloc(1280UL*2560*2);

  // upfront conversions + emb copy + bar zero + m0fused tail, ONE launch
  cvt7m_kernel<<<3904, 256, 0, stream>>>(attm, attt, Wm, Wt, Wmm, Wih, emb,
      attm_bf, attt_bf, Wm_bf, Wt_bf, Wmm_bf, Wih_bf, mm_inp_bf,
      Wli, bli, m0_bf, bar);

  // temp_mout / temp_tout pre-activations + f_m/f_t plane (one launch)
  gemm_bb2f_kernel<<<dim3(10, 8, 3), 256, 0, stream>>>(
      attm_bf, Wm_bf, bm, moutp, attt_bf, Wt_bf, bt, toutp, 1024, 1024,
      mfeat, tfeat, Wsm, Wst, f_m, f_t);
  // x * softmax(x) -> bf16 straight into mm_inp columns
  rowsmx2_kernel<<<2560, 256, 0, stream>>>(moutp, toutp, mm_inp_bf);
  // mm_out = mm_inp @ Wmm^T + bmm  (bf16 output direct)
  gemm_bb_kernel<<<dim3(10, 4), 256, 0, stream>>>(mm_inp_bf, Wmm_bf, bmm, nullptr,
      nullptr, mm_out_bf, 512, 2560);
  // gate preactivations (x-part) for both LSTMs, one launch
  gemm_x12_kernel<<<dim3(11, 16), 256, 0, stream>>>(m0_bf, mm_out_bf, Wih_bf, bih, bhh, X1, X2);
  // fused persistent LSTM (8 + 80 steps) + 224 Wo-conversion helper blocks
  lstm_fused_kernel<<<256, 256, 0, stream>>>(X1, X2, Whh, hbuf0, hbuf1,
      finalA_bf, bar, Wo, Wo_bf);
  // fused e-projection + masked softmax (both modalities, one launch)
  attscore_kernel<<<2560, 256, 0, stream>>>(finalA_bf, Wsm, bsm, Wst, bst,
      f_m, f_t, lens_m, lens_t, w_m, w_t);
  // weighted sums -> bf16 into finalA_bf cols (both modalities, one launch)
  attapply_kernel<<<dim3(16, 10, 2), 256, 0, stream>>>(w_t, w_m, tfeat, mfeat, finalA_bf);
  // final = finalA_bf @ Wo^T + bo, then in-place log_softmax
  gemm_bb_kernel<<<dim3(10, 79), 256, 0, stream>>>(finalA_bf, Wo_bf, bo, nullptr,
      out, nullptr, 10000, 2560);
  logsmax_kernel<<<1280, 256, 0, stream>>>(out);
}

// Round 11
// 919.827 us; speedup vs baseline: 1.1595x; 1.1595x over previous
//
#include <hip/hip_runtime.h>
#include <hip/hip_bf16.h>
#include <math.h>

// Dims: E=512 M=1024 T=1024 H=512 V=10000 ; B=16 S=80 L=200 ; K=10

typedef __bf16 bf16x8 __attribute__((ext_vector_type(8)));
typedef float f32x4 __attribute__((ext_vector_type(4)));
typedef unsigned short u16x8 __attribute__((ext_vector_type(8)));

__device__ inline unsigned short f2b(float f){
  union { float f; unsigned u; } v; v.f = f;
  unsigned u = v.u;
  u += 0x7fff + ((u >> 16) & 1);       // round-to-nearest-even
  return (unsigned short)(u >> 16);
}
__device__ inline float b2f(unsigned short u){
  union { unsigned u; float f; } v; v.u = (unsigned)u << 16; return v.f;
}
__device__ inline float sigm(float x){ return 1.f/(1.f + __expf(-x)); }
__device__ inline float tanh_fast(float x){
  float e = __expf(2.f*x);
  return 1.f - 2.f/(e + 1.f);
}
__device__ inline float wred_max(float v){ for (int o=32;o;o>>=1) v = fmaxf(v, __shfl_xor(v,o)); return v; }
__device__ inline float wred_sum(float v){ for (int o=32;o;o>>=1) v += __shfl_xor(v,o); return v; }

__device__ inline float bred_max(float v, float* sm){
  v = wred_max(v);
  int w = threadIdx.x >> 6;
  if ((threadIdx.x & 63) == 0) sm[w] = v;
  __syncthreads();
  v = fmaxf(fmaxf(sm[0], sm[1]), fmaxf(sm[2], sm[3]));
  __syncthreads();
  return v;
}
__device__ inline float bred_sum(float v, float* sm){
  v = wred_sum(v);
  int w = threadIdx.x >> 6;
  if ((threadIdx.x & 63) == 0) sm[w] = v;
  __syncthreads();
  v = sm[0] + sm[1] + sm[2] + sm[3];
  __syncthreads();
  return v;
}

#define GLOAD_LDS16(g, l) __builtin_amdgcn_global_load_lds( \
    (const __attribute__((address_space(1))) void*)(g), \
    (__attribute__((address_space(3))) void*)(l), 16, 0, 0)

__global__ void zero_kernel(int* p, int n){
  int i = blockIdx.x*64 + threadIdx.x;
  if (i < n) p[i] = 0;
}

// ---------------------------------------------------------------------------
// One fused f32->bf16 conversion pass for all 7 upfront conversions.
// Segments (8-elem chunks): attm 163840 | attt 163840 | Wm 131072 | Wt 131072
// | Wmm 163840 | Wih 131072 | emb 81920 (strided dst into mm_inp cols [0,512))
// total = 966656 chunks = 3776 blocks x 256.
// ---------------------------------------------------------------------------
__global__ void cvt7_kernel(
    const float* __restrict__ attm, const float* __restrict__ attt,
    const float* __restrict__ Wm,   const float* __restrict__ Wt,
    const float* __restrict__ Wmm,  const float* __restrict__ Wih,
    const float* __restrict__ emb,
    unsigned short* __restrict__ attm_bf, unsigned short* __restrict__ attt_bf,
    unsigned short* __restrict__ Wm_bf,   unsigned short* __restrict__ Wt_bf,
    unsigned short* __restrict__ Wmm_bf,  unsigned short* __restrict__ Wih_bf,
    unsigned short* __restrict__ mm_inp_bf)
{
  int i = blockIdx.x*256 + threadIdx.x;
  const float* s; unsigned short* d; int o;
  if (i < 458752){
    if (i < 163840){ s = attm; d = attm_bf; o = i; }
    else if (i < 327680){ s = attt; d = attt_bf; o = i - 163840; }
    else { s = Wm; d = Wm_bf; o = i - 327680; }
  } else if (i < 753664){
    if (i < 589824){ s = Wt; d = Wt_bf; o = i - 458752; }
    else { s = Wmm; d = Wmm_bf; o = i - 589824; }
  } else {
    if (i < 884736){ s = Wih; d = Wih_bf; o = i - 753664; }
    else { s = emb; d = mm_inp_bf; o = i - 884736; }
  }
  f32x4 a = ((const f32x4*)s)[(size_t)o*2];
  f32x4 b = ((const f32x4*)s)[(size_t)o*2+1];
  u16x8 v;
  v[0]=f2b(a[0]); v[1]=f2b(a[1]); v[2]=f2b(a[2]); v[3]=f2b(a[3]);
  v[4]=f2b(b[0]); v[5]=f2b(b[1]); v[6]=f2b(b[2]); v[7]=f2b(b[3]);
  if (i >= 884736){
    int row = o >> 6, c8 = (o & 63) << 3;
    *(u16x8*)&d[(size_t)row*2560 + c8] = v;
  } else {
    ((u16x8*)d)[o] = v;
  }
}

// ---------------------------------------------------------------------------
// Shared GEMM body: C = A @ B^T + b1 + b2.  A:(R,K) bf16, B:(N,K) bf16.
// Output: f32 to C, or bf16 to Cbf if Cbf != nullptr.
// 128x128 tile, BK=32, 256 thr. global_load_lds staging.
// ---------------------------------------------------------------------------
__device__ __forceinline__ void gemm_body(
    const unsigned short* __restrict__ A, const unsigned short* __restrict__ B,
    const float* __restrict__ bias1, const float* __restrict__ bias2,
    float* __restrict__ C, unsigned short* __restrict__ Cbf, int N, int K,
    unsigned short* lA, unsigned short* lB, int r0, int n0)
{
  int tid = threadIdx.x;
  int w = tid >> 6, lane = tid & 63;
  int wr = (w >> 1) << 6, wc = (w & 1) << 6;
  int lm = lane & 15, lq = lane >> 4;
  f32x4 acc[4][4] = {};

  int row0 = tid >> 2, row1 = (tid + 256) >> 2, cc = (tid & 3) << 3;
  const unsigned short* Ag0 = A + (size_t)(r0 + row0)*K + cc;
  const unsigned short* Ag1 = A + (size_t)(r0 + row1)*K + cc;
  int br0 = n0 + row0; if (br0 >= N) br0 = N - 1;
  int br1 = n0 + row1; if (br1 >= N) br1 = N - 1;
  const unsigned short* Bg0 = B + (size_t)br0*K + cc;
  const unsigned short* Bg1 = B + (size_t)br1*K + cc;
  unsigned lb0 = (unsigned)(tid & ~63) * 8;   // u16 index, wave-uniform
  unsigned lb1 = 2048 + lb0;

  for (int k0 = 0; k0 < K; k0 += 32){
    GLOAD_LDS16(Ag0 + k0, &lA[lb0]);
    GLOAD_LDS16(Ag1 + k0, &lA[lb1]);
    GLOAD_LDS16(Bg0 + k0, &lB[lb0]);
    GLOAD_LDS16(Bg1 + k0, &lB[lb1]);
    __syncthreads();
    bf16x8 af[4], bfr[4];
#pragma unroll
    for (int i=0;i<4;i++){
      af[i]  = *(const bf16x8*)&lA[(wr + i*16 + lm)*32 + lq*8];
      bfr[i] = *(const bf16x8*)&lB[(wc + i*16 + lm)*32 + lq*8];
    }
#pragma unroll
    for (int i=0;i<4;i++)
#pragma unroll
      for (int j=0;j<4;j++)
        acc[i][j] = __builtin_amdgcn_mfma_f32_16x16x32_bf16(af[i], bfr[j], acc[i][j], 0, 0, 0);
    __syncthreads();
  }
#pragma unroll
  for (int i=0;i<4;i++){
    int rbase = r0 + wr + i*16 + lq*4;
#pragma unroll
    for (int j=0;j<4;j++){
      int n = n0 + wc + j*16 + lm;
      if (n < N){
        float bv = (bias1 ? bias1[n] : 0.f) + (bias2 ? bias2[n] : 0.f);
        if (Cbf){
#pragma unroll
          for (int rr=0;rr<4;rr++)
            Cbf[(size_t)(rbase + rr)*N + n] = f2b(acc[i][j][rr] + bv);
        } else {
#pragma unroll
          for (int rr=0;rr<4;rr++)
            C[(size_t)(rbase + rr)*N + n] = acc[i][j][rr] + bv;
        }
      }
    }
  }
}

__global__ __launch_bounds__(256) void gemm_bb_kernel(
    const unsigned short* __restrict__ A, const unsigned short* __restrict__ B,
    const float* __restrict__ bias1, const float* __restrict__ bias2,
    float* __restrict__ C, unsigned short* __restrict__ Cbf, int N, int K)
{
  __shared__ unsigned short lA[128*32];
  __shared__ unsigned short lB[128*32];
  gemm_body(A, B, bias1, bias2, C, Cbf, N, K, lA, lB, blockIdx.x << 7, blockIdx.y << 7);
}

// two same-shape GEMMs in one launch (blockIdx.z selects)
__global__ __launch_bounds__(256) void gemm_bb2_kernel(
    const unsigned short* __restrict__ A0, const unsigned short* __restrict__ B0,
    const float* __restrict__ b0, float* __restrict__ C0,
    const unsigned short* __restrict__ A1, const unsigned short* __restrict__ B1,
    const float* __restrict__ b1, float* __restrict__ C1, int N, int K)
{
  __shared__ unsigned short lA[128*32];
  __shared__ unsigned short lB[128*32];
  if (blockIdx.z == 0) gemm_body(A0, B0, b0, nullptr, C0, nullptr, N, K, lA, lB, blockIdx.x << 7, blockIdx.y << 7);
  else                 gemm_body(A1, B1, b1, nullptr, C1, nullptr, N, K, lA, lB, blockIdx.x << 7, blockIdx.y << 7);
}

// X1 (128x2048, A=m0_bf) and X2 (1280x2048, A=mm_out_bf) in one launch.
// grid (11,16): x==0 -> X1 tile; x in [1,10] -> X2 row-tile x-1.
__global__ __launch_bounds__(256) void gemm_x12_kernel(
    const unsigned short* __restrict__ m0_bf, const unsigned short* __restrict__ mmo_bf,
    const unsigned short* __restrict__ Wih_bf,
    const float* __restrict__ bih, const float* __restrict__ bhh,
    float* __restrict__ X1, float* __restrict__ X2)
{
  __shared__ unsigned short lA[128*32];
  __shared__ unsigned short lB[128*32];
  if (blockIdx.x == 0)
    gemm_body(m0_bf, Wih_bf, bih, bhh, X1, nullptr, 2048, 512, lA, lB, 0, blockIdx.y << 7);
  else
    gemm_body(mmo_bf, Wih_bf, bih, bhh, X2, nullptr, 2048, 512, lA, lB, (blockIdx.x - 1) << 7, blockIdx.y << 7);
}

// ---------------------------------------------------------------------------
// y = x * softmax(x) over rows of 1024; merged pair -> bf16 into mm_inp cols
// ---------------------------------------------------------------------------
__global__ __launch_bounds__(256) void rowsmx2_kernel(const float* __restrict__ X0,
    const float* __restrict__ X1, unsigned short* __restrict__ out)
{
  __shared__ float sm[4];
  int bx = blockIdx.x, tid = threadIdx.x;
  int row = (bx < 1280) ? bx : bx - 1280;
  const float* xr = ((bx < 1280) ? X0 : X1) + (size_t)row * 1024;
  int ooff = (bx < 1280) ? 1536 : 512;
  float x[4];
#pragma unroll
  for (int j=0;j<4;j++) x[j] = xr[j*256 + tid];
  float m = fmaxf(fmaxf(x[0],x[1]), fmaxf(x[2],x[3]));
  m = bred_max(m, sm);
  float s = 0.f;
#pragma unroll
  for (int j=0;j<4;j++) s += __expf(x[j]-m);
  s = bred_sum(s, sm);
  float inv = 1.f / s;
  unsigned short* o = out + (size_t)row*2560 + ooff;
#pragma unroll
  for (int j=0;j<4;j++) o[j*256 + tid] = f2b(x[j] * (__expf(x[j]-m) * inv));
}

// ---------------------------------------------------------------------------
// fused avgpool (row of 204 means into LDS) + m0 GEMV, writing bf16 directly
// ---------------------------------------------------------------------------
__global__ __launch_bounds__(256) void m0fused_kernel(
    const float* __restrict__ tempo, const float* __restrict__ motion,
    const float* __restrict__ Wli, const float* __restrict__ bli,
    unsigned short* __restrict__ m0_bf)
{
  __shared__ float rowv[204];
  int bx = blockIdx.x, tid = threadIdx.x;
  int b = bx >> 3, s = bx & 7;
  if (tid < 204){
    int c = tid;
    const float* src = (c < 102) ? (tempo  + ((size_t)(b*80 + s*10))*1024 + c*10)
                                 : (motion + ((size_t)(b*80 + s*10))*1024 + (c-102)*10);
    float acc = 0.f;
    for (int r=0;r<10;r++){
      const float* p = src + (size_t)r*1024;
#pragma unroll
      for (int cc=0;cc<10;cc++) acc += p[cc];
    }
    rowv[c] = acc * 0.01f;
  }
  __syncthreads();
  for (int c = tid; c < 512; c += 256){
    const float* w = Wli + (size_t)c*204;
    float acc = bli[c];
    for (int k=0;k<204;k++) acc += rowv[k]*w[k];
    m0_bf[(size_t)bx*512 + c] = f2b(acc);
  }
}

// ---------------------------------------------------------------------------
// Persistent fused LSTM -- round-0 protocol (3.34 us/step floor with the
// original half-exchange; ~4.1us/step with the correct full-h exchange).
// r1/r3/r4 protocol redesigns all regressed; r9/r10 proved the r7 helper
// arrangement (Wo nt-unpaced + f unpaced inside this dispatch) is optimal:
// interference ~6-15us << the ~37us serial cost of doing it elsewhere.
// act stored bf16-only (attscore reads bf16).  THIS KERNEL == r7 VERBATIM.
// ---------------------------------------------------------------------------
#define LSTM_NBLK 32
#define HP 520   // padded row stride (u16 elems)

__global__ __launch_bounds__(256) void lstm_fused_kernel(
    const float* __restrict__ X1, const float* __restrict__ X2,
    const float* __restrict__ Whh,
    unsigned long long* __restrict__ hb0, unsigned long long* __restrict__ hb1,
    unsigned short* __restrict__ finalA_bf,
    int* __restrict__ bar,
    const float* __restrict__ Wo, unsigned short* __restrict__ Wo_bf,
    const float* __restrict__ mfeat, const float* __restrict__ tfeat,
    const float* __restrict__ Wsm, const float* __restrict__ Wst,
    float* __restrict__ f_m, float* __restrict__ f_t)
{
  __shared__ unsigned short w_lds[64*HP];   // 66560 B
  __shared__ unsigned short h_lds[16*HP];   // 16640 B
  __shared__ float gb[4][16][16];           // 4096 B
  __shared__ unsigned short hstage[16][16]; // 512 B [batch][unit]
  int tid = threadIdx.x, j = blockIdx.x;

  if (j >= LSTM_NBLK){
    // ---------------- helper blocks: LSTM-independent work ----------------
    int hb = j - LSTM_NBLK;                 // 0..223
    // (a) Wo f32 -> bf16 : nontemporal reads (102 MB, never reused)
    const f32x4* wp = (const f32x4*)Wo;
    for (int ch = hb*256 + tid; ch < 3200000; ch += 224*256){
      f32x4 a = __builtin_nontemporal_load(wp + (size_t)ch*2);
      f32x4 b = __builtin_nontemporal_load(wp + (size_t)ch*2 + 1);
      u16x8 o;
      o[0]=f2b(a[0]); o[1]=f2b(a[1]); o[2]=f2b(a[2]); o[3]=f2b(a[3]);
      o[4]=f2b(b[0]); o[5]=f2b(b[1]); o[6]=f2b(b[2]); o[7]=f2b(b[3]);
      ((u16x8*)Wo_bf)[ch] = o;              // cached: Wo GEMM re-reads from LLC
    }
    // (b) f_m[r] = dot(mfeat[r], Wsm[512:1536)) ; f_t likewise. 6400 wave-rows.
    int wv = hb*4 + (tid >> 6);             // 0..895
    int lane = tid & 63;
    for (int r = wv; r < 6400; r += 896){
      const float* a = (r < 3200) ? (mfeat + (size_t)r*1024) : (tfeat + (size_t)(r-3200)*1024);
      const float* wvec = (r < 3200) ? (Wsm + 512) : (Wst + 512);
      float acc = 0.f;
      for (int c = lane; c < 1024; c += 64) acc += a[c]*wvec[c];
      acc = wred_sum(acc);
      if (lane == 0){ if (r < 3200) f_m[r] = acc; else f_t[r-3200] = acc; }
    }
    return;
  }

  // ---------------- recurrence blocks: round-0 protocol ----------------
  int j16 = j*16;
  int lane = tid & 63, w = tid >> 6;
  int lm = lane & 15, lq = lane >> 4;

  // ---- preload Whh slice (rows g*512 + j16 + u), f32 -> bf16, once ----
  for (int i = 0; i < 16; i++){
    int ch = tid + i*256;              // 4096 chunks of 8
    int r = ch >> 6, c8 = (ch & 63) << 3;
    int grow = (r >> 4)*512 + j16 + (r & 15);
    const float* s = Whh + (size_t)grow*512 + c8;
    f32x4 a = ((const f32x4*)s)[0], b = ((const f32x4*)s)[1];
    u16x8 o;
    o[0]=f2b(a[0]); o[1]=f2b(a[1]); o[2]=f2b(a[2]); o[3]=f2b(a[3]);
    o[4]=f2b(b[0]); o[5]=f2b(b[1]); o[6]=f2b(b[2]); o[7]=f2b(b[3]);
    *(u16x8*)&w_lds[r*HP + c8] = o;
  }

  float c_reg = 0.f;
  int ul = tid & 15, bb = tid >> 4;
  unsigned long long* hbufs[2] = { hb0, hb1 };
  const int wbase = ((w << 4) + lm)*HP;
  const int abase = lm*HP;
  const int koff = lq << 3;
  int sc = 0;

  for (int seg = 0; seg < 2; seg++){
    const float* Xp = seg ? X2 : X1;
    int Tst = seg ? 80 : 8;
    for (int t = 0; t < Tst; t++){
      // ---- wait for previous step's h to be at the LLC ----
      if (sc > 0){
        if (tid == 0){
          while (__hip_atomic_load(&bar[sc-1], __ATOMIC_RELAXED, __HIP_MEMORY_SCOPE_AGENT) < LSTM_NBLK)
            __builtin_amdgcn_s_sleep(1);
        }
        __syncthreads();
      }
      // ---- X gate biases for this step (independent of h; overlaps h load) ----
      size_t xrow = ((size_t)bb*Tst + t)*2048 + j16 + ul;
      float xi = Xp[xrow];
      float xf = Xp[xrow + 512];
      float xg = Xp[xrow + 1024];
      float xo = Xp[xrow + 1536];
      // ---- load h state into LDS (LLC-coherent atomic loads) ----
      if (sc == 0){
        u16x8 z = {0,0,0,0,0,0,0,0};
        for (int i = tid; i < 1024; i += 256){
          int b = i >> 6, c8 = (i & 63) << 3;
          *(u16x8*)&h_lds[b*HP + c8] = z;
        }
      } else {
        const unsigned long long* src = hbufs[sc & 1];
#pragma unroll
        for (int it = 0; it < 8; it++){
          int i = tid + it*256;               // u64 chunk: b = i>>7, c64 = i&127
          int b = i >> 7, c64 = i & 127;
          unsigned long long v = __hip_atomic_load(&src[i], __ATOMIC_RELAXED, __HIP_MEMORY_SCOPE_AGENT);
          *(unsigned long long*)&h_lds[b*HP + (c64 << 2)] = v;
        }
      }
      __syncthreads();
      // ---- gates: wave w computes gate w for 16 units x 16 batches ----
      f32x4 a0 = {0.f,0.f,0.f,0.f}, a1 = {0.f,0.f,0.f,0.f};
#pragma unroll
      for (int k0 = 0; k0 < 512; k0 += 64){
        bf16x8 ha = *(const bf16x8*)&h_lds[abase + k0 + koff];
        bf16x8 wa = *(const bf16x8*)&w_lds[wbase + k0 + koff];
        a0 = __builtin_amdgcn_mfma_f32_16x16x32_bf16(ha, wa, a0, 0, 0, 0);
        bf16x8 hbf = *(const bf16x8*)&h_lds[abase + k0 + 32 + koff];
        bf16x8 wbf = *(const bf16x8*)&w_lds[wbase + k0 + 32 + koff];
        a1 = __builtin_amdgcn_mfma_f32_16x16x32_bf16(hbf, wbf, a1, 0, 0, 0);
      }
      f32x4 acc = a0 + a1;
      *(f32x4*)&gb[w][lm][lq << 2] = acc;   // gb[gate][unit][batch]
      __syncthreads();
      // ---- cell update: thread = (batch bb, unit ul) ----
      float iv = gb[0][ul][bb] + xi;
      float fv = gb[1][ul][bb] + xf;
      float gv = gb[2][ul][bb] + xg;
      float ov = gb[3][ul][bb] + xo;
      c_reg = sigm(fv)*c_reg + sigm(iv)*tanh_fast(gv);
      float hn = sigm(ov)*tanh_fast(c_reg);
      hstage[bb][ul] = f2b(hn);
      __syncthreads();
      // ---- publish h slice to LLC (wave 0: 64 x 8B coherent stores) ----
      if (tid < 64){
        int b = tid >> 2, ch = tid & 3;
        unsigned long long v = *(const unsigned long long*)&hstage[b][ch << 2];
        unsigned long long* dst = hbufs[(sc + 1) & 1] + (size_t)b*128 + (j << 2) + ch;
        __hip_atomic_store(dst, v, __ATOMIC_RELAXED, __HIP_MEMORY_SCOPE_AGENT);
      }
      sc++;
      __syncthreads();   // vmcnt(0) drain: h publish ack'd at LLC
      if (tid == 0)
        __hip_atomic_fetch_add(&bar[sc-1], 1, __ATOMIC_RELAXED, __HIP_MEMORY_SCOPE_AGENT);
      // act store AFTER the flag: off the cross-block critical path
      if (seg)
        finalA_bf[(size_t)(bb*80 + t)*2560 + j16 + ul] = f2b(tanh_fast(hn));
    }
  }
}

// ---------------------------------------------------------------------------
// fused attention scores: e = act[:, :512] @ we + b (bf16 act), then masked
// softmax over (e + f).  2560 blocks: [0,1280) tempo, [1280,2560) motion.
// ---------------------------------------------------------------------------
__global__ __launch_bounds__(256) void attscore_kernel(
    const unsigned short* __restrict__ finalA_bf,
    const float* __restrict__ Wsm, const float* __restrict__ bsm,
    const float* __restrict__ Wst, const float* __restrict__ bst,
    const float* __restrict__ f_m, const float* __restrict__ f_t,
    const int* __restrict__ lens_m, const int* __restrict__ lens_t,
    float* __restrict__ w_m, float* __restrict__ w_t)
{
  __shared__ float sm[4];
  int bx = blockIdx.x, tid = threadIdx.x;
  bool mside = bx >= 1280;
  int row = mside ? bx - 1280 : bx;
  const float* wv = mside ? Wsm : Wst;
  float bias = (mside ? bsm : bst)[0];
  const float* f = mside ? f_m : f_t;
  const int* lens = mside ? lens_m : lens_t;
  float* w = mside ? w_m : w_t;
  const unsigned short* a = finalA_bf + (size_t)row*2560;
  float d = b2f(a[tid])*wv[tid] + b2f(a[256+tid])*wv[256+tid];
  float e = bred_sum(d, sm) + bias;
  int b = row/80;
  int len = lens[b];
  bool ok = (tid < 200) && (tid < len);
  float val = ok ? (e + f[b*200 + tid]) : -1e30f;
  float m = bred_max(val, sm);
  float ex = ok ? __expf(val - m) : 0.f;
  float s = bred_sum(ex, sm);
  if (tid < 200) w[(size_t)row*200 + tid] = ex / s;
}

// out[b, s, :] = sum_l w[b,s,l] * feats[b,l,:] -> bf16 into finalA_bf.
// SBLK=16 rows per block (r10 lesson applied as the SINGLE change this round):
// halves the feats re-read factor 10x -> 5x (262 -> 131 MB), still
// memory-bound (~21us) since VALU is ~11us.  grid (16,5,2):
// z=0 tempo->cols[512,1536), z=1 motion->cols[1536,2560).
__global__ __launch_bounds__(256) void attapply_kernel(
    const float* __restrict__ w_t, const float* __restrict__ w_m,
    const float* __restrict__ tfeat, const float* __restrict__ mfeat,
    unsigned short* __restrict__ finalA_bf)
{
  __shared__ float lw[16][200];
  int b = blockIdx.x, sg = blockIdx.y, z = blockIdx.z;
  const float* w = z ? w_m : w_t;
  const float* feats = z ? mfeat : tfeat;
  int coloff = z ? 1536 : 512;
  int tid = threadIdx.x;
  for (int i = tid; i < 3200; i += 256){
    int ss = i / 200, l = i - ss*200;
    lw[ss][l] = w[(size_t)(b*80 + sg*16 + ss)*200 + l];
  }
  __syncthreads();
  float4 acc[16];
#pragma unroll
  for (int s=0;s<16;s++) acc[s] = make_float4(0,0,0,0);
  const float* fb = feats + (size_t)b*200*1024 + tid*4;
  for (int l=0;l<200;l++){
    float4 v = *(const float4*)(fb + (size_t)l*1024);
#pragma unroll
    for (int s=0;s<16;s++){
      float wv = lw[s][l];
      acc[s].x += wv*v.x; acc[s].y += wv*v.y; acc[s].z += wv*v.z; acc[s].w += wv*v.w;
    }
  }
#pragma unroll
  for (int s=0;s<16;s++){
    ushort4 o;
    o.x = f2b(acc[s].x); o.y = f2b(acc[s].y); o.z = f2b(acc[s].z); o.w = f2b(acc[s].w);
    *(ushort4*)&finalA_bf[(size_t)(b*80 + sg*16 + s)*2560 + coloff + tid*4] = o;
  }
}

// in-place log_softmax over rows of 10000
__global__ __launch_bounds__(256) void logsmax_kernel(float* __restrict__ out)
{
  __shared__ float buf[10000];
  __shared__ float sm[4];
  int row = blockIdx.x, tid = threadIdx.x;
  float* o = out + (size_t)row * 10000;
  float m = -1e30f;
  for (int i = tid; i < 10000; i += 256){ float v = o[i]; buf[i] = v; m = fmaxf(m, v); }
  m = bred_max(m, sm);
  float s = 0.f;
  for (int i = tid; i < 10000; i += 256) s += __expf(buf[i] - m);
  s = bred_sum(s, sm);
  float lse = m + __logf(s);
  for (int i = tid; i < 10000; i += 256) o[i] = buf[i] - lse;
}

// ---------------------------------------------------------------------------
extern "C" void kernel_launch(void* const* d_in, const int* in_sizes, int n_in,
                              void* d_out, int out_size, void* d_ws, size_t ws_size,
                              hipStream_t stream)
{
  const float* mfeat = (const float*)d_in[0];
  const float* tfeat = (const float*)d_in[1];
  const float* attm  = (const float*)d_in[2];
  const float* attt  = (const float*)d_in[3];
  const float* emb   = (const float*)d_in[4];
  const int* lens_m  = (const int*)d_in[5];
  const int* lens_t  = (const int*)d_in[6];
  const float* Wm  = (const float*)d_in[8];
  const float* bm  = (const float*)d_in[9];
  const float* Wt  = (const float*)d_in[10];
  const float* bt  = (const float*)d_in[11];
  const float* Wmm = (const float*)d_in[12];
  const float* bmm = (const float*)d_in[13];
  const float* Wli = (const float*)d_in[14];
  const float* bli = (const float*)d_in[15];
  const float* Wih = (const float*)d_in[16];
  const float* Whh = (const float*)d_in[17];
  const float* bih = (const float*)d_in[18];
  const float* bhh = (const float*)d_in[19];
  const float* Wsm = (const float*)d_in[20];
  const float* bsm = (const float*)d_in[21];
  const float* Wst = (const float*)d_in[22];
  const float* bst = (const float*)d_in[23];
  const float* Wo  = (const float*)d_in[24];
  const float* bo  = (const float*)d_in[25];
  float* out = (float*)d_out;

  char* ws = (char*)d_ws;
  size_t off = 0;
  auto alloc = [&](size_t bytes)->void* {
    void* p = (void*)(ws + off);
    off += (bytes + 255) & ~(size_t)255;
    return p;
  };
  // f32 scratch
  float* moutp  = (float*)alloc(1280UL*1024*4);
  float* toutp  = (float*)alloc(1280UL*1024*4);
  float* X1     = (float*)alloc(128UL*2048*4);
  float* X2     = (float*)alloc(1280UL*2048*4);
  float* f_m = (float*)alloc(3200UL*4); float* f_t = (float*)alloc(3200UL*4);
  float* w_m = (float*)alloc(1280UL*200*4); float* w_t = (float*)alloc(1280UL*200*4);
  int* bar = (int*)alloc(128*4);
  // bf16 / u64 scratch
  unsigned long long* hbuf0 = (unsigned long long*)alloc(16UL*128*8);
  unsigned long long* hbuf1 = (unsigned long long*)alloc(16UL*128*8);
  unsigned short* attm_bf   = (unsigned short*)alloc(1280UL*1024*2);
  unsigned short* attt_bf   = (unsigned short*)alloc(1280UL*1024*2);
  unsigned short* Wm_bf     = (unsigned short*)alloc(1024UL*1024*2);
  unsigned short* Wt_bf     = (unsigned short*)alloc(1024UL*1024*2);
  unsigned short* Wmm_bf    = (unsigned short*)alloc(512UL*2560*2);
  unsigned short* Wih_bf    = (unsigned short*)alloc(2048UL*512*2);
  unsigned short* Wo_bf     = (unsigned short*)alloc(10000UL*2560*2);
  unsigned short* mm_inp_bf = (unsigned short*)alloc(1280UL*2560*2);
  unsigned short* mm_out_bf = (unsigned short*)alloc(1280UL*512*2);
  unsigned short* m0_bf     = (unsigned short*)alloc(128UL*512*2);
  unsigned short* finalA_bf = (unsigned short*)alloc(1280UL*2560*2);

  // all upfront f32->bf16 conversions + emb copy in ONE launch
  cvt7_kernel<<<3776, 256, 0, stream>>>(attm, attt, Wm, Wt, Wmm, Wih, emb,
      attm_bf, attt_bf, Wm_bf, Wt_bf, Wmm_bf, Wih_bf, mm_inp_bf);
  zero_kernel<<<2, 64, 0, stream>>>(bar, 128);

  // temp_mout / temp_tout pre-activations (one 160-block launch)
  gemm_bb2_kernel<<<dim3(10, 8, 2), 256, 0, stream>>>(
      attm_bf, Wm_bf, bm, moutp, attt_bf, Wt_bf, bt, toutp, 1024, 1024);
  // x * softmax(x) -> bf16 straight into mm_inp columns
  rowsmx2_kernel<<<2560, 256, 0, stream>>>(moutp, toutp, mm_inp_bf);
  // mm_out = mm_inp @ Wmm^T + bmm  (bf16 output direct)
  gemm_bb_kernel<<<dim3(10, 4), 256, 0, stream>>>(mm_inp_bf, Wmm_bf, bmm, nullptr,
      nullptr, mm_out_bf, 512, 2560);
  // fused avgpool + m0 GEMV (bf16 output direct)
  m0fused_kernel<<<128, 256, 0, stream>>>(attt, attm, Wli, bli, m0_bf);
  // gate preactivations (x-part) for both LSTMs, one launch
  gemm_x12_kernel<<<dim3(11, 16), 256, 0, stream>>>(m0_bf, mm_out_bf, Wih_bf, bih, bhh, X1, X2);
  // fused persistent LSTM (8 + 80 steps) + 224 helper blocks (Wo cvt, f_m/f_t)
  lstm_fused_kernel<<<256, 256, 0, stream>>>(X1, X2, Whh, hbuf0, hbuf1,
      finalA_bf, bar, Wo, Wo_bf, mfeat, tfeat, Wsm, Wst, f_m, f_t);
  // fused e-projection + masked softmax (both modalities, one launch)
  attscore_kernel<<<2560, 256, 0, stream>>>(finalA_bf, Wsm, bsm, Wst, bst,
      f_m, f_t, lens_m, lens_t, w_m, w_t);
  // weighted sums -> bf16 into finalA_bf cols (both modalities, one launch)
  attapply_kernel<<<dim3(16, 5, 2), 256, 0, stream>>>(w_t, w_m, tfeat, mfeat, finalA_bf);
  // final = finalA_bf @ Wo^T + bo, then in-place log_softmax
  gemm_bb_kernel<<<dim3(10, 79), 256, 0, stream>>>(finalA_bf, Wo_bf, bo, nullptr,
      out, nullptr, 10000, 2560);
  logsmax_kernel<<<1280, 256, 0, stream>>>(out);
}

// Round 12
// 917.448 us; speedup vs baseline: 1.1625x; 1.0026x over previous
//
#include <hip/hip_runtime.h>
#include <hip/hip_bf16.h>
#include <math.h>

// Dims: E=512 M=1024 T=1024 H=512 V=10000 ; B=16 S=80 L=200 ; K=10

typedef __bf16 bf16x8 __attribute__((ext_vector_type(8)));
typedef float f32x4 __attribute__((ext_vector_type(4)));
typedef unsigned short u16x8 __attribute__((ext_vector_type(8)));

__device__ inline unsigned short f2b(float f){
  union { float f; unsigned u; } v; v.f = f;
  unsigned u = v.u;
  u += 0x7fff + ((u >> 16) & 1);       // round-to-nearest-even
  return (unsigned short)(u >> 16);
}
__device__ inline float b2f(unsigned short u){
  union { unsigned u; float f; } v; v.u = (unsigned)u << 16; return v.f;
}
__device__ inline float sigm(float x){ return 1.f/(1.f + __expf(-x)); }
__device__ inline float tanh_fast(float x){
  float e = __expf(2.f*x);
  return 1.f - 2.f/(e + 1.f);
}
__device__ inline float wred_max(float v){ for (int o=32;o;o>>=1) v = fmaxf(v, __shfl_xor(v,o)); return v; }
__device__ inline float wred_sum(float v){ for (int o=32;o;o>>=1) v += __shfl_xor(v,o); return v; }

__device__ inline float bred_max(float v, float* sm){
  v = wred_max(v);
  int w = threadIdx.x >> 6;
  if ((threadIdx.x & 63) == 0) sm[w] = v;
  __syncthreads();
  v = fmaxf(fmaxf(sm[0], sm[1]), fmaxf(sm[2], sm[3]));
  __syncthreads();
  return v;
}
__device__ inline float bred_sum(float v, float* sm){
  v = wred_sum(v);
  int w = threadIdx.x >> 6;
  if ((threadIdx.x & 63) == 0) sm[w] = v;
  __syncthreads();
  v = sm[0] + sm[1] + sm[2] + sm[3];
  __syncthreads();
  return v;
}

#define GLOAD_LDS16(g, l) __builtin_amdgcn_global_load_lds( \
    (const __attribute__((address_space(1))) void*)(g), \
    (__attribute__((address_space(3))) void*)(l), 16, 0, 0)

// ---------------------------------------------------------------------------
// One fused f32->bf16 conversion pass for all 7 upfront conversions.
// Segments (8-elem chunks): attm 163840 | attt 163840 | Wm 131072 | Wt 131072
// | Wmm 163840 | Wih 131072 | emb 81920 (strided dst into mm_inp cols [0,512))
// total = 966656 chunks = 3776 blocks x 256.  Block 0 also zeroes bar[1024]
// (proven pattern from r8/r9 cvt8).
// ---------------------------------------------------------------------------
__global__ void cvt7_kernel(
    const float* __restrict__ attm, const float* __restrict__ attt,
    const float* __restrict__ Wm,   const float* __restrict__ Wt,
    const float* __restrict__ Wmm,  const float* __restrict__ Wih,
    const float* __restrict__ emb,
    unsigned short* __restrict__ attm_bf, unsigned short* __restrict__ attt_bf,
    unsigned short* __restrict__ Wm_bf,   unsigned short* __restrict__ Wt_bf,
    unsigned short* __restrict__ Wmm_bf,  unsigned short* __restrict__ Wih_bf,
    unsigned short* __restrict__ mm_inp_bf, int* __restrict__ bar)
{
  int i = blockIdx.x*256 + threadIdx.x;
  if (blockIdx.x == 0){
#pragma unroll
    for (int k = 0; k < 4; k++) bar[threadIdx.x + k*256] = 0;
  }
  const float* s; unsigned short* d; int o;
  if (i < 458752){
    if (i < 163840){ s = attm; d = attm_bf; o = i; }
    else if (i < 327680){ s = attt; d = attt_bf; o = i - 163840; }
    else { s = Wm; d = Wm_bf; o = i - 327680; }
  } else if (i < 753664){
    if (i < 589824){ s = Wt; d = Wt_bf; o = i - 458752; }
    else { s = Wmm; d = Wmm_bf; o = i - 589824; }
  } else {
    if (i < 884736){ s = Wih; d = Wih_bf; o = i - 753664; }
    else { s = emb; d = mm_inp_bf; o = i - 884736; }
  }
  f32x4 a = ((const f32x4*)s)[(size_t)o*2];
  f32x4 b = ((const f32x4*)s)[(size_t)o*2+1];
  u16x8 v;
  v[0]=f2b(a[0]); v[1]=f2b(a[1]); v[2]=f2b(a[2]); v[3]=f2b(a[3]);
  v[4]=f2b(b[0]); v[5]=f2b(b[1]); v[6]=f2b(b[2]); v[7]=f2b(b[3]);
  if (i >= 884736){
    int row = o >> 6, c8 = (o & 63) << 3;
    *(u16x8*)&d[(size_t)row*2560 + c8] = v;
  } else {
    ((u16x8*)d)[o] = v;
  }
}

// ---------------------------------------------------------------------------
// Shared GEMM body: C = A @ B^T + b1 + b2.  A:(R,K) bf16, B:(N,K) bf16.
// Output: f32 to C, or bf16 to Cbf if Cbf != nullptr.
// 128x128 tile, BK=32, 256 thr. global_load_lds staging.
// ---------------------------------------------------------------------------
__device__ __forceinline__ void gemm_body(
    const unsigned short* __restrict__ A, const unsigned short* __restrict__ B,
    const float* __restrict__ bias1, const float* __restrict__ bias2,
    float* __restrict__ C, unsigned short* __restrict__ Cbf, int N, int K,
    unsigned short* lA, unsigned short* lB, int r0, int n0)
{
  int tid = threadIdx.x;
  int w = tid >> 6, lane = tid & 63;
  int wr = (w >> 1) << 6, wc = (w & 1) << 6;
  int lm = lane & 15, lq = lane >> 4;
  f32x4 acc[4][4] = {};

  int row0 = tid >> 2, row1 = (tid + 256) >> 2, cc = (tid & 3) << 3;
  const unsigned short* Ag0 = A + (size_t)(r0 + row0)*K + cc;
  const unsigned short* Ag1 = A + (size_t)(r0 + row1)*K + cc;
  int br0 = n0 + row0; if (br0 >= N) br0 = N - 1;
  int br1 = n0 + row1; if (br1 >= N) br1 = N - 1;
  const unsigned short* Bg0 = B + (size_t)br0*K + cc;
  const unsigned short* Bg1 = B + (size_t)br1*K + cc;
  unsigned lb0 = (unsigned)(tid & ~63) * 8;   // u16 index, wave-uniform
  unsigned lb1 = 2048 + lb0;

  for (int k0 = 0; k0 < K; k0 += 32){
    GLOAD_LDS16(Ag0 + k0, &lA[lb0]);
    GLOAD_LDS16(Ag1 + k0, &lA[lb1]);
    GLOAD_LDS16(Bg0 + k0, &lB[lb0]);
    GLOAD_LDS16(Bg1 + k0, &lB[lb1]);
    __syncthreads();
    bf16x8 af[4], bfr[4];
#pragma unroll
    for (int i=0;i<4;i++){
      af[i]  = *(const bf16x8*)&lA[(wr + i*16 + lm)*32 + lq*8];
      bfr[i] = *(const bf16x8*)&lB[(wc + i*16 + lm)*32 + lq*8];
    }
#pragma unroll
    for (int i=0;i<4;i++)
#pragma unroll
      for (int j=0;j<4;j++)
        acc[i][j] = __builtin_amdgcn_mfma_f32_16x16x32_bf16(af[i], bfr[j], acc[i][j], 0, 0, 0);
    __syncthreads();
  }
#pragma unroll
  for (int i=0;i<4;i++){
    int rbase = r0 + wr + i*16 + lq*4;
#pragma unroll
    for (int j=0;j<4;j++){
      int n = n0 + wc + j*16 + lm;
      if (n < N){
        float bv = (bias1 ? bias1[n] : 0.f) + (bias2 ? bias2[n] : 0.f);
        if (Cbf){
#pragma unroll
          for (int rr=0;rr<4;rr++)
            Cbf[(size_t)(rbase + rr)*N + n] = f2b(acc[i][j][rr] + bv);
        } else {
#pragma unroll
          for (int rr=0;rr<4;rr++)
            C[(size_t)(rbase + rr)*N + n] = acc[i][j][rr] + bv;
        }
      }
    }
  }
}

__global__ __launch_bounds__(256) void gemm_bb_kernel(
    const unsigned short* __restrict__ A, const unsigned short* __restrict__ B,
    const float* __restrict__ bias1, const float* __restrict__ bias2,
    float* __restrict__ C, unsigned short* __restrict__ Cbf, int N, int K)
{
  __shared__ unsigned short lA[128*32];
  __shared__ unsigned short lB[128*32];
  gemm_body(A, B, bias1, bias2, C, Cbf, N, K, lA, lB, blockIdx.x << 7, blockIdx.y << 7);
}

// two same-shape GEMMs in one launch (blockIdx.z selects)
__global__ __launch_bounds__(256) void gemm_bb2_kernel(
    const unsigned short* __restrict__ A0, const unsigned short* __restrict__ B0,
    const float* __restrict__ b0, float* __restrict__ C0,
    const unsigned short* __restrict__ A1, const unsigned short* __restrict__ B1,
    const float* __restrict__ b1, float* __restrict__ C1, int N, int K)
{
  __shared__ unsigned short lA[128*32];
  __shared__ unsigned short lB[128*32];
  if (blockIdx.z == 0) gemm_body(A0, B0, b0, nullptr, C0, nullptr, N, K, lA, lB, blockIdx.x << 7, blockIdx.y << 7);
  else                 gemm_body(A1, B1, b1, nullptr, C1, nullptr, N, K, lA, lB, blockIdx.x << 7, blockIdx.y << 7);
}

// X1 (128x2048, A=m0_bf) and X2 (1280x2048, A=mm_out_bf) in one launch.
// grid (11,16): x==0 -> X1 tile; x in [1,10] -> X2 row-tile x-1.
__global__ __launch_bounds__(256) void gemm_x12_kernel(
    const unsigned short* __restrict__ m0_bf, const unsigned short* __restrict__ mmo_bf,
    const unsigned short* __restrict__ Wih_bf,
    const float* __restrict__ bih, const float* __restrict__ bhh,
    float* __restrict__ X1, float* __restrict__ X2)
{
  __shared__ unsigned short lA[128*32];
  __shared__ unsigned short lB[128*32];
  if (blockIdx.x == 0)
    gemm_body(m0_bf, Wih_bf, bih, bhh, X1, nullptr, 2048, 512, lA, lB, 0, blockIdx.y << 7);
  else
    gemm_body(mmo_bf, Wih_bf, bih, bhh, X2, nullptr, 2048, 512, lA, lB, (blockIdx.x - 1) << 7, blockIdx.y << 7);
}

// ---------------------------------------------------------------------------
// y = x * softmax(x) over rows of 1024; merged pair -> bf16 into mm_inp cols
// ---------------------------------------------------------------------------
__global__ __launch_bounds__(256) void rowsmx2_kernel(const float* __restrict__ X0,
    const float* __restrict__ X1, unsigned short* __restrict__ out)
{
  __shared__ float sm[4];
  int bx = blockIdx.x, tid = threadIdx.x;
  int row = (bx < 1280) ? bx : bx - 1280;
  const float* xr = ((bx < 1280) ? X0 : X1) + (size_t)row * 1024;
  int ooff = (bx < 1280) ? 1536 : 512;
  float x[4];
#pragma unroll
  for (int j=0;j<4;j++) x[j] = xr[j*256 + tid];
  float m = fmaxf(fmaxf(x[0],x[1]), fmaxf(x[2],x[3]));
  m = bred_max(m, sm);
  float s = 0.f;
#pragma unroll
  for (int j=0;j<4;j++) s += __expf(x[j]-m);
  s = bred_sum(s, sm);
  float inv = 1.f / s;
  unsigned short* o = out + (size_t)row*2560 + ooff;
#pragma unroll
  for (int j=0;j<4;j++) o[j*256 + tid] = f2b(x[j] * (__expf(x[j]-m) * inv));
}

// ---------------------------------------------------------------------------
// fused avgpool (row of 204 means into LDS) + m0 GEMV, writing bf16 directly
// ---------------------------------------------------------------------------
__global__ __launch_bounds__(256) void m0fused_kernel(
    const float* __restrict__ tempo, const float* __restrict__ motion,
    const float* __restrict__ Wli, const float* __restrict__ bli,
    unsigned short* __restrict__ m0_bf)
{
  __shared__ float rowv[204];
  int bx = blockIdx.x, tid = threadIdx.x;
  int b = bx >> 3, s = bx & 7;
  if (tid < 204){
    int c = tid;
    const float* src = (c < 102) ? (tempo  + ((size_t)(b*80 + s*10))*1024 + c*10)
                                 : (motion + ((size_t)(b*80 + s*10))*1024 + (c-102)*10);
    float acc = 0.f;
    for (int r=0;r<10;r++){
      const float* p = src + (size_t)r*1024;
#pragma unroll
      for (int cc=0;cc<10;cc++) acc += p[cc];
    }
    rowv[c] = acc * 0.01f;
  }
  __syncthreads();
  for (int c = tid; c < 512; c += 256){
    const float* w = Wli + (size_t)c*204;
    float acc = bli[c];
    for (int k=0;k<204;k++) acc += rowv[k]*w[k];
    m0_bf[(size_t)bx*512 + c] = f2b(acc);
  }
}

// ---------------------------------------------------------------------------
// Persistent fused LSTM -- r11 structure with ONE change: the 32x same-address
// fetch_add (serialized RMW chain at one LLC coherence point, est. 0.7-1.3us
// of the 4.1us step) is replaced by 32 MONOTONIC per-block flags, one per
// 128B line.  Producer tid0: plain relaxed store of sc AFTER the
// vmcnt(0)-draining __syncthreads (transitivity preserved: observing
// flag>=sc implies that block's h stores are ack'd at the LLC).  Consumer:
// wave-0 lanes 0-31 poll one line each in parallel (r3-validated pattern;
// r3's slowness was its 4x redundant direct-LLC h loads, not adopted here).
// Helpers (Wo nt-unpaced + f) unchanged from r7/r11 optimum.
// ---------------------------------------------------------------------------
#define LSTM_NBLK 32
#define HP 520   // padded row stride (u16 elems)

__global__ __launch_bounds__(256) void lstm_fused_kernel(
    const float* __restrict__ X1, const float* __restrict__ X2,
    const float* __restrict__ Whh,
    unsigned long long* __restrict__ hb0, unsigned long long* __restrict__ hb1,
    unsigned short* __restrict__ finalA_bf,
    int* __restrict__ bar,
    const float* __restrict__ Wo, unsigned short* __restrict__ Wo_bf,
    const float* __restrict__ mfeat, const float* __restrict__ tfeat,
    const float* __restrict__ Wsm, const float* __restrict__ Wst,
    float* __restrict__ f_m, float* __restrict__ f_t)
{
  __shared__ unsigned short w_lds[64*HP];   // 66560 B
  __shared__ unsigned short h_lds[16*HP];   // 16640 B
  __shared__ float gb[4][16][16];           // 4096 B
  __shared__ unsigned short hstage[16][16]; // 512 B [batch][unit]
  int tid = threadIdx.x, j = blockIdx.x;

  if (j >= LSTM_NBLK){
    // ---------------- helper blocks: LSTM-independent work ----------------
    int hb = j - LSTM_NBLK;                 // 0..223
    // (a) Wo f32 -> bf16 : nontemporal reads (102 MB, never reused)
    const f32x4* wp = (const f32x4*)Wo;
    for (int ch = hb*256 + tid; ch < 3200000; ch += 224*256){
      f32x4 a = __builtin_nontemporal_load(wp + (size_t)ch*2);
      f32x4 b = __builtin_nontemporal_load(wp + (size_t)ch*2 + 1);
      u16x8 o;
      o[0]=f2b(a[0]); o[1]=f2b(a[1]); o[2]=f2b(a[2]); o[3]=f2b(a[3]);
      o[4]=f2b(b[0]); o[5]=f2b(b[1]); o[6]=f2b(b[2]); o[7]=f2b(b[3]);
      ((u16x8*)Wo_bf)[ch] = o;              // cached: Wo GEMM re-reads from LLC
    }
    // (b) f_m[r] = dot(mfeat[r], Wsm[512:1536)) ; f_t likewise. 6400 wave-rows.
    int wv = hb*4 + (tid >> 6);             // 0..895
    int lane = tid & 63;
    for (int r = wv; r < 6400; r += 896){
      const float* a = (r < 3200) ? (mfeat + (size_t)r*1024) : (tfeat + (size_t)(r-3200)*1024);
      const float* wvec = (r < 3200) ? (Wsm + 512) : (Wst + 512);
      float acc = 0.f;
      for (int c = lane; c < 1024; c += 64) acc += a[c]*wvec[c];
      acc = wred_sum(acc);
      if (lane == 0){ if (r < 3200) f_m[r] = acc; else f_t[r-3200] = acc; }
    }
    return;
  }

  // ---------------- recurrence blocks: round-0 protocol, flag-line sync ----
  int j16 = j*16;
  int lane = tid & 63, w = tid >> 6;
  int lm = lane & 15, lq = lane >> 4;

  // ---- preload Whh slice (rows g*512 + j16 + u), f32 -> bf16, once ----
  for (int i = 0; i < 16; i++){
    int ch = tid + i*256;              // 4096 chunks of 8
    int r = ch >> 6, c8 = (ch & 63) << 3;
    int grow = (r >> 4)*512 + j16 + (r & 15);
    const float* s = Whh + (size_t)grow*512 + c8;
    f32x4 a = ((const f32x4*)s)[0], b = ((const f32x4*)s)[1];
    u16x8 o;
    o[0]=f2b(a[0]); o[1]=f2b(a[1]); o[2]=f2b(a[2]); o[3]=f2b(a[3]);
    o[4]=f2b(b[0]); o[5]=f2b(b[1]); o[6]=f2b(b[2]); o[7]=f2b(b[3]);
    *(u16x8*)&w_lds[r*HP + c8] = o;
  }

  float c_reg = 0.f;
  int ul = tid & 15, bb = tid >> 4;
  unsigned long long* hbufs[2] = { hb0, hb1 };
  const int wbase = ((w << 4) + lm)*HP;
  const int abase = lm*HP;
  const int koff = lq << 3;
  int sc = 0;

  for (int seg = 0; seg < 2; seg++){
    const float* Xp = seg ? X2 : X1;
    int Tst = seg ? 80 : 8;
    for (int t = 0; t < Tst; t++){
      // ---- wait: all 32 per-block flags >= sc (parallel, one line/lane) ----
      if (sc > 0){
        if (tid < 32){
          const int* fp = bar + (tid << 5);   // 128 B per flag line
          while (__hip_atomic_load(fp, __ATOMIC_RELAXED, __HIP_MEMORY_SCOPE_AGENT) < sc)
            __builtin_amdgcn_s_sleep(1);
        }
        __syncthreads();
      }
      // ---- X gate biases for this step (independent of h; overlaps h load) ----
      size_t xrow = ((size_t)bb*Tst + t)*2048 + j16 + ul;
      float xi = Xp[xrow];
      float xf = Xp[xrow + 512];
      float xg = Xp[xrow + 1024];
      float xo = Xp[xrow + 1536];
      // ---- load h state into LDS (LLC-coherent atomic loads) ----
      if (sc == 0){
        u16x8 z = {0,0,0,0,0,0,0,0};
        for (int i = tid; i < 1024; i += 256){
          int b = i >> 6, c8 = (i & 63) << 3;
          *(u16x8*)&h_lds[b*HP + c8] = z;
        }
      } else {
        const unsigned long long* src = hbufs[sc & 1];
#pragma unroll
        for (int it = 0; it < 8; it++){
          int i = tid + it*256;               // u64 chunk: b = i>>7, c64 = i&127
          int b = i >> 7, c64 = i & 127;
          unsigned long long v = __hip_atomic_load(&src[i], __ATOMIC_RELAXED, __HIP_MEMORY_SCOPE_AGENT);
          *(unsigned long long*)&h_lds[b*HP + (c64 << 2)] = v;
        }
      }
      __syncthreads();
      // ---- gates: wave w computes gate w for 16 units x 16 batches ----
      f32x4 a0 = {0.f,0.f,0.f,0.f}, a1 = {0.f,0.f,0.f,0.f};
#pragma unroll
      for (int k0 = 0; k0 < 512; k0 += 64){
        bf16x8 ha = *(const bf16x8*)&h_lds[abase + k0 + koff];
        bf16x8 wa = *(const bf16x8*)&w_lds[wbase + k0 + koff];
        a0 = __builtin_amdgcn_mfma_f32_16x16x32_bf16(ha, wa, a0, 0, 0, 0);
        bf16x8 hbf = *(const bf16x8*)&h_lds[abase + k0 + 32 + koff];
        bf16x8 wbf = *(const bf16x8*)&w_lds[wbase + k0 + 32 + koff];
        a1 = __builtin_amdgcn_mfma_f32_16x16x32_bf16(hbf, wbf, a1, 0, 0, 0);
      }
      f32x4 acc = a0 + a1;
      *(f32x4*)&gb[w][lm][lq << 2] = acc;   // gb[gate][unit][batch]
      __syncthreads();
      // ---- cell update: thread = (batch bb, unit ul) ----
      float iv = gb[0][ul][bb] + xi;
      float fv = gb[1][ul][bb] + xf;
      float gv = gb[2][ul][bb] + xg;
      float ov = gb[3][ul][bb] + xo;
      c_reg = sigm(fv)*c_reg + sigm(iv)*tanh_fast(gv);
      float hn = sigm(ov)*tanh_fast(c_reg);
      hstage[bb][ul] = f2b(hn);
      __syncthreads();
      // ---- publish h slice to LLC (wave 0: 64 x 8B coherent stores) ----
      if (tid < 64){
        int b = tid >> 2, ch = tid & 3;
        unsigned long long v = *(const unsigned long long*)&hstage[b][ch << 2];
        unsigned long long* dst = hbufs[(sc + 1) & 1] + (size_t)b*128 + (j << 2) + ch;
        __hip_atomic_store(dst, v, __ATOMIC_RELAXED, __HIP_MEMORY_SCOPE_AGENT);
      }
      sc++;
      __syncthreads();   // vmcnt(0) drain: h publish ack'd at LLC past here
      if (tid == 0)
        __hip_atomic_store(&bar[j << 5], sc, __ATOMIC_RELAXED, __HIP_MEMORY_SCOPE_AGENT);
      // act store AFTER the flag: off the cross-block critical path
      if (seg)
        finalA_bf[(size_t)(bb*80 + t)*2560 + j16 + ul] = f2b(tanh_fast(hn));
    }
  }
}

// ---------------------------------------------------------------------------
// fused attention scores: e = act[:, :512] @ we + b (bf16 act), then masked
// softmax over (e + f).  2560 blocks: [0,1280) tempo, [1280,2560) motion.
// ---------------------------------------------------------------------------
__global__ __launch_bounds__(256) void attscore_kernel(
    const unsigned short* __restrict__ finalA_bf,
    const float* __restrict__ Wsm, const float* __restrict__ bsm,
    const float* __restrict__ Wst, const float* __restrict__ bst,
    const float* __restrict__ f_m, const float* __restrict__ f_t,
    const int* __restrict__ lens_m, const int* __restrict__ lens_t,
    float* __restrict__ w_m, float* __restrict__ w_t)
{
  __shared__ float sm[4];
  int bx = blockIdx.x, tid = threadIdx.x;
  bool mside = bx >= 1280;
  int row = mside ? bx - 1280 : bx;
  const float* wv = mside ? Wsm : Wst;
  float bias = (mside ? bsm : bst)[0];
  const float* f = mside ? f_m : f_t;
  const int* lens = mside ? lens_m : lens_t;
  float* w = mside ? w_m : w_t;
  const unsigned short* a = finalA_bf + (size_t)row*2560;
  float d = b2f(a[tid])*wv[tid] + b2f(a[256+tid])*wv[256+tid];
  float e = bred_sum(d, sm) + bias;
  int b = row/80;
  int len = lens[b];
  bool ok = (tid < 200) && (tid < len);
  float val = ok ? (e + f[b*200 + tid]) : -1e30f;
  float m = bred_max(val, sm);
  float ex = ok ? __expf(val - m) : 0.f;
  float s = bred_sum(ex, sm);
  if (tid < 200) w[(size_t)row*200 + tid] = ex / s;
}

// out[b, s, :] = sum_l w[b,s,l] * feats[b,l,:] -> bf16 into finalA_bf.
// SBLK=16 rows per block (r11 win): re-read factor 5x (131 MB), memory-bound
// ~21us.  grid (16,5,2): z=0 tempo->cols[512,1536), z=1 motion->[1536,2560).
__global__ __launch_bounds__(256) void attapply_kernel(
    const float* __restrict__ w_t, const float* __restrict__ w_m,
    const float* __restrict__ tfeat, const float* __restrict__ mfeat,
    unsigned short* __restrict__ finalA_bf)
{
  __shared__ float lw[16][200];
  int b = blockIdx.x, sg = blockIdx.y, z = blockIdx.z;
  const float* w = z ? w_m : w_t;
  const float* feats = z ? mfeat : tfeat;
  int coloff = z ? 1536 : 512;
  int tid = threadIdx.x;
  for (int i = tid; i < 3200; i += 256){
    int ss = i / 200, l = i - ss*200;
    lw[ss][l] = w[(size_t)(b*80 + sg*16 + ss)*200 + l];
  }
  __syncthreads();
  float4 acc[16];
#pragma unroll
  for (int s=0;s<16;s++) acc[s] = make_float4(0,0,0,0);
  const float* fb = feats + (size_t)b*200*1024 + tid*4;
  for (int l=0;l<200;l++){
    float4 v = *(const float4*)(fb + (size_t)l*1024);
#pragma unroll
    for (int s=0;s<16;s++){
      float wv = lw[s][l];
      acc[s].x += wv*v.x; acc[s].y += wv*v.y; acc[s].z += wv*v.z; acc[s].w += wv*v.w;
    }
  }
#pragma unroll
  for (int s=0;s<16;s++){
    ushort4 o;
    o.x = f2b(acc[s].x); o.y = f2b(acc[s].y); o.z = f2b(acc[s].z); o.w = f2b(acc[s].w);
    *(ushort4*)&finalA_bf[(size_t)(b*80 + sg*16 + s)*2560 + coloff + tid*4] = o;
  }
}

// in-place log_softmax over rows of 10000
__global__ __launch_bounds__(256) void logsmax_kernel(float* __restrict__ out)
{
  __shared__ float buf[10000];
  __shared__ float sm[4];
  int row = blockIdx.x, tid = threadIdx.x;
  float* o = out + (size_t)row * 10000;
  float m = -1e30f;
  for (int i = tid; i < 10000; i += 256){ float v = o[i]; buf[i] = v; m = fmaxf(m, v); }
  m = bred_max(m, sm);
  float s = 0.f;
  for (int i = tid; i < 10000; i += 256) s += __expf(buf[i] - m);
  s = bred_sum(s, sm);
  float lse = m + __logf(s);
  for (int i = tid; i < 10000; i += 256) o[i] = buf[i] - lse;
}

// ---------------------------------------------------------------------------
extern "C" void kernel_launch(void* const* d_in, const int* in_sizes, int n_in,
                              void* d_out, int out_size, void* d_ws, size_t ws_size,
                              hipStream_t stream)
{
  const float* mfeat = (const float*)d_in[0];
  const float* tfeat = (const float*)d_in[1];
  const float* attm  = (const float*)d_in[2];
  const float* attt  = (const float*)d_in[3];
  const float* emb   = (const float*)d_in[4];
  const int* lens_m  = (const int*)d_in[5];
  const int* lens_t  = (const int*)d_in[6];
  const float* Wm  = (const float*)d_in[8];
  const float* bm  = (const float*)d_in[9];
  const float* Wt  = (const float*)d_in[10];
  const float* bt  = (const float*)d_in[11];
  const float* Wmm = (const float*)d_in[12];
  const float* bmm = (const float*)d_in[13];
  const float* Wli = (const float*)d_in[14];
  const float* bli = (const float*)d_in[15];
  const float* Wih = (const float*)d_in[16];
  const float* Whh = (const float*)d_in[17];
  const float* bih = (const float*)d_in[18];
  const float* bhh = (const float*)d_in[19];
  const float* Wsm = (const float*)d_in[20];
  const float* bsm = (const float*)d_in[21];
  const float* Wst = (const float*)d_in[22];
  const float* bst = (const float*)d_in[23];
  const float* Wo  = (const float*)d_in[24];
  const float* bo  = (const float*)d_in[25];
  float* out = (float*)d_out;

  char* ws = (char*)d_ws;
  size_t off = 0;
  auto alloc = [&](size_t bytes)->void* {
    void* p = (void*)(ws + off);
    off += (bytes + 255) & ~(size_t)255;
    return p;
  };
  // f32 scratch
  float* moutp  = (float*)alloc(1280UL*1024*4);
  float* toutp  = (float*)alloc(1280UL*1024*4);
  float* X1     = (float*)alloc(128UL*2048*4);
  float* X2     = (float*)alloc(1280UL*2048*4);
  float* f_m = (float*)alloc(3200UL*4); float* f_t = (float*)alloc(3200UL*4);
  float* w_m = (float*)alloc(1280UL*200*4); float* w_t = (float*)alloc(1280UL*200*4);
  int* bar = (int*)alloc(32UL*32*4);     // 32 monotonic flags, one 128B line each
  // bf16 / u64 scratch
  unsigned long long* hbuf0 = (unsigned long long*)alloc(16UL*128*8);
  unsigned long long* hbuf1 = (unsigned long long*)alloc(16UL*128*8);
  unsigned short* attm_bf   = (unsigned short*)alloc(1280UL*1024*2);
  unsigned short* attt_bf   = (unsigned short*)alloc(1280UL*1024*2);
  unsigned short* Wm_bf     = (unsigned short*)alloc(1024UL*1024*2);
  unsigned short* Wt_bf     = (unsigned short*)alloc(1024UL*1024*2);
  unsigned short* Wmm_bf    = (unsigned short*)alloc(512UL*2560*2);
  unsigned short* Wih_bf    = (unsigned short*)alloc(2048UL*512*2);
  unsigned short* Wo_bf     = (unsigned short*)alloc(10000UL*2560*2);
  unsigned short* mm_inp_bf = (unsigned short*)alloc(1280UL*2560*2);
  unsigned short* mm_out_bf = (unsigned short*)alloc(1280UL*512*2);
  unsigned short* m0_bf     = (unsigned short*)alloc(128UL*512*2);
  unsigned short* finalA_bf = (unsigned short*)alloc(1280UL*2560*2);

  // all upfront f32->bf16 conversions + emb copy + bar zero in ONE launch
  cvt7_kernel<<<3776, 256, 0, stream>>>(attm, attt, Wm, Wt, Wmm, Wih, emb,
      attm_bf, attt_bf, Wm_bf, Wt_bf, Wmm_bf, Wih_bf, mm_inp_bf, bar);

  // temp_mout / temp_tout pre-activations (one 160-block launch)
  gemm_bb2_kernel<<<dim3(10, 8, 2), 256, 0, stream>>>(
      attm_bf, Wm_bf, bm, moutp, attt_bf, Wt_bf, bt, toutp, 1024, 1024);
  // x * softmax(x) -> bf16 straight into mm_inp columns
  rowsmx2_kernel<<<2560, 256, 0, stream>>>(moutp, toutp, mm_inp_bf);
  // mm_out = mm_inp @ Wmm^T + bmm  (bf16 output direct)
  gemm_bb_kernel<<<dim3(10, 4), 256, 0, stream>>>(mm_inp_bf, Wmm_bf, bmm, nullptr,
      nullptr, mm_out_bf, 512, 2560);
  // fused avgpool + m0 GEMV (bf16 output direct)
  m0fused_kernel<<<128, 256, 0, stream>>>(attt, attm, Wli, bli, m0_bf);
  // gate preactivations (x-part) for both LSTMs, one launch
  gemm_x12_kernel<<<dim3(11, 16), 256, 0, stream>>>(m0_bf, mm_out_bf, Wih_bf, bih, bhh, X1, X2);
  // fused persistent LSTM (8 + 80 steps) + 224 helper blocks (Wo cvt, f_m/f_t)
  lstm_fused_kernel<<<256, 256, 0, stream>>>(X1, X2, Whh, hbuf0, hbuf1,
      finalA_bf, bar, Wo, Wo_bf, mfeat, tfeat, Wsm, Wst, f_m, f_t);
  // fused e-projection + masked softmax (both modalities, one launch)
  attscore_kernel<<<2560, 256, 0, stream>>>(finalA_bf, Wsm, bsm, Wst, bst,
      f_m, f_t, lens_m, lens_t, w_m, w_t);
  // weighted sums -> bf16 into finalA_bf cols (both modalities, one launch)
  attapply_kernel<<<dim3(16, 5, 2), 256, 0, stream>>>(w_t, w_m, tfeat, mfeat, finalA_bf);
  // final = finalA_bf @ Wo^T + bo, then in-place log_softmax
  gemm_bb_kernel<<<dim3(10, 79), 256, 0, stream>>>(finalA_bf, Wo_bf, bo, nullptr,
      out, nullptr, 10000, 2560);
  logsmax_kernel<<<1280, 256, 0, stream>>>(out);
}